// Round 11
// baseline (221.744 us; speedup 1.0000x reference)
//
#include <hip/hip_runtime.h>
#include <math.h>

#define IMG   512
#define TILE  64
#define HALO  9                  // 8 (gauss) + 1 (sobel)
#define BROWS 66                 // output rows/cols incl. sobel ring
#define MROWS 82                 // mean rows needed (TILE + 2*HALO)
#define SSTR  67                 // 67%32=3 coprime -> strided access conflict-free

__device__ __forceinline__ int reflect_idx(int i) {
    // numpy 'symmetric': -1 -> 0, -2 -> 1, ..., N -> N-1
    if (i < 0) i = -i - 1;
    if (i >= IMG) i = 2 * IMG - 1 - i;
    return i;
}

__global__ __launch_bounds__(256, 4) void sobel_fused(
    const float* __restrict__ x, float* __restrict__ out)
{
    __shared__ float sB[MROWS * SSTR];   // 21976 B : W-blurred rows [82][66 used]
    __shared__ float sC[BROWS * SSTR];   // 17688 B : fully blurred + zero ring

    const int t  = threadIdx.x;
    const int w0 = blockIdx.x * TILE;
    const int h0 = blockIdx.y * TILE;
    const int b  = blockIdx.z;

    // 17-tap gaussian (sigma=2): unnormalized exp constants (<=1ulp vs f32 expf),
    // normalization constant-folds at compile time.
    const float ge[9] = {1.0f, 0.882496903f, 0.606530660f, 0.324652467f,
                         0.135335283f, 0.0439369336f, 0.0111089965f,
                         0.00218749112f, 0.000335462628f};
    float gw[17];
    {
        float s = 0.f;
        #pragma unroll
        for (int i = 0; i < 17; ++i) { gw[i] = ge[(i < 8) ? (8 - i) : (i - 8)]; s += gw[i]; }
        float inv = 1.0f / s;
        #pragma unroll
        for (int i = 0; i < 17; ++i) gw[i] *= inv;
    }

    const float* xb = x + (size_t)b * 3 * IMG * IMG;
    const float third = 1.0f / 3.0f;

    // ---- phase A: per-ROW channel-mean + W-blur (contiguous vector loads) ----
    // unit = (mean-row r in [0,82)) x (col-seg in [0,3)); seg covers sB cols
    // c0..c0+23 (seg 2: c0..65). v[0] = mean at global col (w0 + c0 - 9).
    if (t < 246) {
        int r   = t % 82;
        int seg = t / 82;
        int c0  = seg * 24;                         // 0, 24, 48
        int gr  = reflect_idx(h0 - HALO + r);
        const float* rowp = xb + (size_t)gr * IMG;
        int startc = w0 + c0 - HALO;                // global col of v[0]
        int abase  = startc - 3;                    // ≡ 0 (mod 4): 16B-aligned
        float v[40];
        if (abase >= 0 && abase + 44 <= IMG) {
            // fast path: 11 aligned float4 per channel, all indices static
            const float* pa = rowp + abase;
            #pragma unroll
            for (int q = 0; q < 11; ++q) {
                float4 a = *(const float4*)(pa + 4 * q);
                float4 bb = *(const float4*)(pa + IMG * IMG + 4 * q);
                float4 cc = *(const float4*)(pa + 2 * IMG * IMG + 4 * q);
                float m0 = (a.x + bb.x + cc.x) * third;
                float m1 = (a.y + bb.y + cc.y) * third;
                float m2 = (a.z + bb.z + cc.z) * third;
                float m3 = (a.w + bb.w + cc.w) * third;
                int i0 = 4 * q - 3;                 // v index of component .x
                if (i0 >= 0)      v[i0]     = m0;
                if (i0 + 1 >= 0)  v[i0 + 1] = m1;
                if (i0 + 2 >= 0)  v[i0 + 2] = m2;
                if (i0 + 3 < 40)  v[i0 + 3] = m3;
            }
        } else {
            // edge path: scalar with W-reflect
            #pragma unroll
            for (int i = 0; i < 40; ++i) {
                int gc = reflect_idx(startc + i);
                const float* p = rowp + gc;
                v[i] = (p[0] + p[IMG * IMG] + p[2 * IMG * IMG]) * third;
            }
        }
        #pragma unroll
        for (int j = 0; j < 24; ++j) {
            if (c0 + j < BROWS) {
                float a = 0.f;
                #pragma unroll
                for (int k = 0; k < 17; ++k) a += gw[k] * v[j + k];
                sB[r * SSTR + c0 + j] = a;          // stride 67: CF (2-way max)
            }
        }
    }
    __syncthreads();

    // ---- phase B: H-blur down sB columns; zero-ring; -> sC ----
    // unit = (col c in [0,66)) x (row-seg in [0,3)); 22 output rows per unit
    if (t < 198) {
        int c   = t % 66;
        int seg = t / 66;
        int r0  = seg * 22;
        float v[38];
        #pragma unroll
        for (int i = 0; i < 38; ++i) v[i] = sB[(r0 + i) * SSTR + c];  // lane-consec c: CF
        int gcol = w0 - 1 + c;
        bool cin = (gcol >= 0) & (gcol < IMG);
        #pragma unroll
        for (int j = 0; j < 22; ++j) {
            float a = 0.f;
            #pragma unroll
            for (int k = 0; k < 17; ++k) a += gw[k] * v[j + k];
            int grow = h0 - 1 + r0 + j;
            bool in = cin & (grow >= 0) & (grow < IMG);
            sC[(r0 + j) * SSTR + c] = in ? a : 0.f; // stride 67: CF
        }
    }
    __syncthreads();

    // ---- phase C: 3x3 sobel + hypot; 16 output rows per thread ----
    {
        int c  = t & 63;
        int rq = t >> 6;                       // 0..3
        #pragma unroll
        for (int it = 0; it < 4; ++it) {
            int r0 = (rq + it * 4) * 4;        // 0,4,...,60
            const float* bp = sC + r0 * SSTR + c;
            float m[6][3];
            #pragma unroll
            for (int rr = 0; rr < 6; ++rr) {
                #pragma unroll
                for (int cc = 0; cc < 3; ++cc)
                    m[rr][cc] = bp[rr * SSTR + cc];
            }
            #pragma unroll
            for (int dr = 0; dr < 4; ++dr) {
                float tl = m[dr][0],   tm = m[dr][1],   tr = m[dr][2];
                float ml = m[dr+1][0],                  mr = m[dr+1][2];
                float bl = m[dr+2][0], bm = m[dr+2][1], br2 = m[dr+2][2];
                float sx = (bl - tl) + 2.f * (bm - tm) + (br2 - tr);
                float sy = (tr - tl) + 2.f * (mr - ml) + (br2 - bl);
                out[((size_t)b * IMG + (h0 + r0 + dr)) * IMG + (w0 + c)]
                    = sqrtf(sx * sx + sy * sy);
            }
        }
    }
}

extern "C" void kernel_launch(void* const* d_in, const int* in_sizes, int n_in,
                              void* d_out, int out_size, void* d_ws, size_t ws_size,
                              hipStream_t stream) {
    const float* x = (const float*)d_in[0];
    float* out = (float*)d_out;
    dim3 grid(IMG / TILE, IMG / TILE, 32);   // 8 x 8 x 32 = 2048 blocks
    dim3 block(256);
    hipLaunchKernelGGL(sobel_fused, grid, block, 0, stream, x, out);
}

// Round 17
// 170.039 us; speedup vs baseline: 1.3041x; 1.3041x over previous
//
#include <hip/hip_runtime.h>
#include <math.h>

#define IMG   512
#define TW    64                 // tile width  (output cols per block)
#define TH    32                 // tile height (output rows per block)
#define HALO  9                  // 8 (gauss) + 1 (sobel)
#define HROWS 34                 // TH + 2 : H-blurred rows (incl sobel ring)
#define BSTR  83                 // 83%32=19 coprime -> strided access CF
#define CSTR  67                 // 67%32=3  coprime -> strided access CF

__device__ __forceinline__ int reflect_idx(int i) {
    // numpy 'symmetric': -1 -> 0, -2 -> 1, ..., N -> N-1
    if (i < 0) i = -i - 1;
    if (i >= IMG) i = 2 * IMG - 1 - i;
    return i;
}

__global__ __launch_bounds__(256) void sobel_fused(
    const float* __restrict__ x, float* __restrict__ out)
{
    __shared__ float sB[HROWS * BSTR];   // 11288 B : H-blurred ch-SUM [34][82 used]
    __shared__ float sC[HROWS * CSTR];   // 9112 B  : fully blurred (3x) + zero ring
                                         // total 20400 B -> 8 blocks/CU

    const int t  = threadIdx.x;
    const int w0 = blockIdx.x * TW;
    const int h0 = blockIdx.y * TH;
    const int b  = blockIdx.z;

    // 17-tap gaussian (sigma=2), normalized by 1/s ONLY. The channel-mean 1/3
    // is applied ONCE at the final write (sobel+hypot are 1-homogeneous in the
    // blur, so blur(sum) = 3*blur(mean) -> out = (1/3)*hypot).
    const float ge[9] = {1.0f, 0.882496903f, 0.606530660f, 0.324652467f,
                         0.135335283f, 0.0439369336f, 0.0111089965f,
                         0.00218749112f, 0.000335462628f};
    float gw[17];
    {
        float s = 0.f;
        #pragma unroll
        for (int i = 0; i < 17; ++i) { gw[i] = ge[(i < 8) ? (8 - i) : (i - 8)]; s += gw[i]; }
        float inv = 1.0f / s;
        #pragma unroll
        for (int i = 0; i < 17; ++i) gw[i] *= inv;
    }
    const float third = 1.0f / 3.0f;

    const float* xb = x + (size_t)b * 3 * IMG * IMG;

    // ---- phase A: channel-sum + H-blur (single path, coalesced) ----
    // unit = (mean-col c in 0..81, row-seg in 0..2); seg covers sB rows
    // j0..j0+11 (seg 2: 10 rows). v[i] = ch-sum at mean row (h0-9+j0+i).
    if (t < 246) {
        int c   = t % 82;
        int seg = t / 82;
        int j0  = seg * 12;
        int gc  = reflect_idx(w0 - HALO + c);        // lane-consecutive: coalesced
        const float* colp = xb + gc;
        float v[28];
        #pragma unroll
        for (int i = 0; i < 28; ++i) {
            int gr = reflect_idx(h0 - HALO + j0 + i);
            const float* p = colp + (size_t)gr * IMG;
            v[i] = p[0] + p[IMG * IMG] + p[2 * IMG * IMG];
        }
        #pragma unroll
        for (int j = 0; j < 12; ++j) {
            if (j0 + j < HROWS) {
                float a = 0.f;
                #pragma unroll
                for (int k = 0; k < 17; ++k) a += gw[k] * v[j + k];
                sB[(j0 + j) * BSTR + c] = a;         // lane-consec c: CF
            }
        }
    }
    __syncthreads();

    // ---- phase B: W-blur along sB rows; zero-ring; -> sC ----
    // unit = (row rr in 0..33, col-seg in 0..5); 11 output cols per unit
    if (t < 204) {
        int rr  = t % 34;
        int seg = t / 34;
        int c0  = seg * 11;
        float v[27];
        #pragma unroll
        for (int i = 0; i < 27; ++i) v[i] = sB[rr * BSTR + c0 + i];  // stride 83: CF
        int grow = h0 - 1 + rr;
        bool rin = (grow >= 0) & (grow < IMG);
        #pragma unroll
        for (int j = 0; j < 11; ++j) {
            float a = 0.f;
            #pragma unroll
            for (int k = 0; k < 17; ++k) a += gw[k] * v[j + k];
            int gcol = w0 - 1 + c0 + j;
            bool in = rin & (gcol >= 0) & (gcol < IMG);
            sC[rr * CSTR + c0 + j] = in ? a : 0.f;   // stride 67: CF
        }
    }
    __syncthreads();

    // ---- phase C: 3x3 sobel + hypot*(1/3); 8 consecutive rows per thread ----
    {
        int c  = t & 63;
        int rq = t >> 6;                   // 0..3
        int r0 = rq * 8;                   // tile rows r0..r0+7
        float w[10][3];
        #pragma unroll
        for (int i = 0; i < 10; ++i) {
            #pragma unroll
            for (int dc = 0; dc < 3; ++dc)
                w[i][dc] = sC[(r0 + i) * CSTR + c + dc];  // lane-consec c: CF
        }
        #pragma unroll
        for (int k = 0; k < 8; ++k) {
            float tl = w[k][0],     tm = w[k][1],     tr = w[k][2];
            float ml = w[k + 1][0],                   mr = w[k + 1][2];
            float bl = w[k + 2][0], bm = w[k + 2][1], br2 = w[k + 2][2];
            float sx = (bl - tl) + 2.f * (bm - tm) + (br2 - tr);
            float sy = (tr - tl) + 2.f * (mr - ml) + (br2 - bl);
            out[((size_t)b * IMG + (h0 + r0 + k)) * IMG + (w0 + c)]
                = third * sqrtf(sx * sx + sy * sy);
        }
    }
}

extern "C" void kernel_launch(void* const* d_in, const int* in_sizes, int n_in,
                              void* d_out, int out_size, void* d_ws, size_t ws_size,
                              hipStream_t stream) {
    const float* x = (const float*)d_in[0];
    float* out = (float*)d_out;
    dim3 grid(IMG / TW, IMG / TH, 32);   // 8 x 16 x 32 = 4096 blocks
    dim3 block(256);
    hipLaunchKernelGGL(sobel_fused, grid, block, 0, stream, x, out);
}